// Round 8
// baseline (226.167 us; speedup 1.0000x reference)
//
#include <hip/hip_runtime.h>
#include <math.h>

#define DIM 1024
#define DEPTH 7
#define PAR 8
#define N_NODES 255   // 2^(DEPTH+1) - 1
#define WIDTH 2040    // PAR * N_NODES
#define MARGIN 0.03f  // |logit| below this -> recompute dot in fp32 (decision safety)

// lane that holds tree p's reduced logit after the fold network (bits 8/16/32)
#define REPLANE(p) ((((p) & 1) << 3) | ((((p) >> 1) & 1) << 4) | ((((p) >> 2) & 1) << 5))

typedef float  float2v  __attribute__((ext_vector_type(2)));
typedef _Float16 half2v __attribute__((ext_vector_type(2)));

__device__ __forceinline__ unsigned short f32_to_bf16(float f) {
    unsigned int u = __float_as_uint(f);
    u += 0x7fffu + ((u >> 16) & 1u);   // RTNE
    return (unsigned short)(u >> 16);
}
__device__ __forceinline__ float bf_lo(unsigned int u) { return __uint_as_float(u << 16); }
__device__ __forceinline__ float bf_hi(unsigned int u) { return __uint_as_float(u & 0xffff0000u); }

__device__ __forceinline__ half2v as_h2(unsigned int u) {
    union { unsigned int u; half2v h; } c; c.u = u; return c.h;
}
__device__ __forceinline__ unsigned int pack_h2(float a, float b) {
    union { half2v h; unsigned int u; } c;
    c.h = (half2v){(_Float16)a, (_Float16)b};   // v_cvt_f16_f32 is RTNE
    return c.u;
}

// f16 dot2 with fp32 accumulate
__device__ __forceinline__ float dot2h(unsigned int a, unsigned int b, float c) {
#if __has_builtin(__builtin_amdgcn_fdot2)
    return __builtin_amdgcn_fdot2(as_h2(a), as_h2(b), c, false);
#else
    half2v ha = as_h2(a), hb = as_h2(b);
    c = fmaf((float)ha.x, (float)hb.x, c);
    return fmaf((float)ha.y, (float)hb.y, c);
#endif
}

// fold two per-lane partial sums into one register, separated by lane bit K
__device__ __forceinline__ float foldK(float a, float b, int K) {
    const bool hi = (threadIdx.x & (unsigned)K) != 0;
    const float keep = hi ? b : a;
    const float send = hi ? a : b;
    return keep + __shfl_xor(send, K, 64);
}

// ---------------------------------------------------------------------------
// W_in f32 -> f16 packed (same [WIDTH][DIM] layout)
// ---------------------------------------------------------------------------
__global__ __launch_bounds__(256) void convert_f16_kernel(
    const float* __restrict__ src, unsigned int* __restrict__ dst, int n4)
{
    int i = (int)(blockIdx.x * blockDim.x + threadIdx.x);
    if (i < n4) {
        float4 v = ((const float4*)src)[i];
        uint2 pk;
        pk.x = pack_h2(v.x, v.y);
        pk.y = pack_h2(v.z, v.w);
        ((uint2*)dst)[i] = pk;
    }
}

// ---------------------------------------------------------------------------
// Transpose + convert: W_out f32 [DIM][WIDTH] -> WoT bf16 [WIDTH][DIM]
// ---------------------------------------------------------------------------
__global__ __launch_bounds__(256) void transpose_bf16_kernel(
    const float* __restrict__ W_out, unsigned short* __restrict__ WoT)
{
    __shared__ float tile[64][65];
    const int w0 = blockIdx.x * 64;
    const int d0 = blockIdx.y * 64;
    const int tid = (int)threadIdx.x;
    const int sub = tid & 15;
    const int grp = tid >> 4;

    #pragma unroll
    for (int pass = 0; pass < 4; ++pass) {
        const int dl = pass * 16 + grp;
        const int wl = sub * 4;
        const int w = w0 + wl;
        const int d = d0 + dl;
        float4 v = make_float4(0.f, 0.f, 0.f, 0.f);
        if (w + 3 < WIDTH) {
            v = *(const float4*)(W_out + (size_t)d * WIDTH + w);
        } else {
            float t0 = (w + 0 < WIDTH) ? W_out[(size_t)d * WIDTH + w + 0] : 0.f;
            float t1 = (w + 1 < WIDTH) ? W_out[(size_t)d * WIDTH + w + 1] : 0.f;
            float t2 = (w + 2 < WIDTH) ? W_out[(size_t)d * WIDTH + w + 2] : 0.f;
            float t3 = (w + 3 < WIDTH) ? W_out[(size_t)d * WIDTH + w + 3] : 0.f;
            v = make_float4(t0, t1, t2, t3);
        }
        tile[dl][wl + 0] = v.x; tile[dl][wl + 1] = v.y;
        tile[dl][wl + 2] = v.z; tile[dl][wl + 3] = v.w;
    }
    __syncthreads();
    #pragma unroll
    for (int pass = 0; pass < 4; ++pass) {
        const int wl = pass * 16 + grp;
        const int dl = sub * 4;
        const int w = w0 + wl;
        if (w < WIDTH) {
            unsigned int b0 = f32_to_bf16(tile[dl + 0][wl]);
            unsigned int b1 = f32_to_bf16(tile[dl + 1][wl]);
            unsigned int b2 = f32_to_bf16(tile[dl + 2][wl]);
            unsigned int b3 = f32_to_bf16(tile[dl + 3][wl]);
            uint2 pk;
            pk.x = b0 | (b1 << 16);
            pk.y = b2 | (b3 << 16);
            *(uint2*)(WoT + (size_t)w * DIM + d0 + dl) = pk;
        }
    }
}

// ---------------------------------------------------------------------------
// Main kernel: TWO ROWS PER WAVE, interleaved. Each row follows the verified
// round-5 structure (f16 dot2 stage-1, fold-network reduce, ballot decisions,
// bf16 pk-fma stage-2, fp32 repair). The two rows' chains are fully
// independent -> 2x in-flight loads and hidden shuffle/silu latency, without
// relying on compiler prefetch (which round-6 showed gets sunk).
// ---------------------------------------------------------------------------
__global__ __launch_bounds__(256) void fff_f16x2_kernel(
    const float* __restrict__ x,            // [B, DIM] f32
    const float* __restrict__ W_in,         // [WIDTH, DIM] f32 (repair only)
    const float* __restrict__ b_in,         // [WIDTH] f32
    const unsigned int* __restrict__ Wh,    // f16 W_in  [WIDTH][DIM/2] dwords
    const unsigned short* __restrict__ WoT, // bf16 W_out^T [WIDTH][DIM]
    float* __restrict__ out,                // [B, DIM] f32
    int B)
{
    const int wpair = (int)((blockIdx.x * blockDim.x + threadIdx.x) >> 6);
    const int lane  = (int)(threadIdx.x & 63);
    const int r0 = 2 * wpair;
    const int r1 = 2 * wpair + 1;
    if (r0 >= B) return;
    const bool has1 = (r1 < B);

    const float* xr0 = x + (size_t)r0 * DIM;
    const float* xr1 = x + (size_t)(has1 ? r1 : r0) * DIM;

    unsigned int xp0[8], xp1[8];
    {
        float4 a0 = *(const float4*)(xr0 + lane * 8 + 0);
        float4 a1 = *(const float4*)(xr0 + lane * 8 + 4);
        float4 a2 = *(const float4*)(xr0 + 512 + lane * 8 + 0);
        float4 a3 = *(const float4*)(xr0 + 512 + lane * 8 + 4);
        float4 b0 = *(const float4*)(xr1 + lane * 8 + 0);
        float4 b1 = *(const float4*)(xr1 + lane * 8 + 4);
        float4 b2 = *(const float4*)(xr1 + 512 + lane * 8 + 0);
        float4 b3 = *(const float4*)(xr1 + 512 + lane * 8 + 4);
        xp0[0] = pack_h2(a0.x, a0.y); xp0[1] = pack_h2(a0.z, a0.w);
        xp0[2] = pack_h2(a1.x, a1.y); xp0[3] = pack_h2(a1.z, a1.w);
        xp0[4] = pack_h2(a2.x, a2.y); xp0[5] = pack_h2(a2.z, a2.w);
        xp0[6] = pack_h2(a3.x, a3.y); xp0[7] = pack_h2(a3.z, a3.w);
        xp1[0] = pack_h2(b0.x, b0.y); xp1[1] = pack_h2(b0.z, b0.w);
        xp1[2] = pack_h2(b1.x, b1.y); xp1[3] = pack_h2(b1.z, b1.w);
        xp1[4] = pack_h2(b2.x, b2.y); xp1[5] = pack_h2(b2.z, b2.w);
        xp1[6] = pack_h2(b3.x, b3.y); xp1[7] = pack_h2(b3.z, b3.w);
    }

    float2v acc0[8], acc1[8];
    #pragma unroll
    for (int i = 0; i < 8; ++i) { acc0[i] = (float2v){0.f, 0.f}; acc1[i] = (float2v){0.f, 0.f}; }

    unsigned long long nodes0 = 0ULL, nodes1 = 0ULL;
    const int myp = ((lane >> 3) & 1) | (((lane >> 4) & 1) << 1) | (((lane >> 5) & 1) << 2);

    #pragma unroll 1
    for (int d = 0; d <= DEPTH; ++d) {
        int g0[PAR], g1[PAR];
        float pa0[PAR], pa1[PAR];

        #pragma unroll
        for (int p = 0; p < PAR; ++p) {
            g0[p] = p * N_NODES + (int)((nodes0 >> (8 * p)) & 0xffULL);
            g1[p] = p * N_NODES + (int)((nodes1 >> (8 * p)) & 0xffULL);
        }

        // Phase A: 16 independent dot chains (2 rows x 8 trees), 32 loads
        #pragma unroll
        for (int p = 0; p < PAR; ++p) {
            const unsigned int* wr0 = Wh + (size_t)g0[p] * (DIM / 2);
            const unsigned int* wr1 = Wh + (size_t)g1[p] * (DIM / 2);
            const uint4 u0 = *(const uint4*)(wr0 + lane * 4);
            const uint4 u1 = *(const uint4*)(wr0 + 256 + lane * 4);
            const uint4 v0 = *(const uint4*)(wr1 + lane * 4);
            const uint4 v1 = *(const uint4*)(wr1 + 256 + lane * 4);
            float s0 = 0.f, s1 = 0.f;
            s0 = dot2h(xp0[0], u0.x, s0);  s1 = dot2h(xp1[0], v0.x, s1);
            s0 = dot2h(xp0[1], u0.y, s0);  s1 = dot2h(xp1[1], v0.y, s1);
            s0 = dot2h(xp0[2], u0.z, s0);  s1 = dot2h(xp1[2], v0.z, s1);
            s0 = dot2h(xp0[3], u0.w, s0);  s1 = dot2h(xp1[3], v0.w, s1);
            s0 = dot2h(xp0[4], u1.x, s0);  s1 = dot2h(xp1[4], v1.x, s1);
            s0 = dot2h(xp0[5], u1.y, s0);  s1 = dot2h(xp1[5], v1.y, s1);
            s0 = dot2h(xp0[6], u1.z, s0);  s1 = dot2h(xp1[6], v1.z, s1);
            s0 = dot2h(xp0[7], u1.w, s0);  s1 = dot2h(xp1[7], v1.w, s1);
            pa0[p] = s0; pa1[p] = s1;
        }

        // Phase B: two interleaved fold networks (independent -> latency hidden)
        const float c01a = foldK(pa0[0], pa0[1], 8),  c01b = foldK(pa1[0], pa1[1], 8);
        const float c23a = foldK(pa0[2], pa0[3], 8),  c23b = foldK(pa1[2], pa1[3], 8);
        const float c45a = foldK(pa0[4], pa0[5], 8),  c45b = foldK(pa1[4], pa1[5], 8);
        const float c67a = foldK(pa0[6], pa0[7], 8),  c67b = foldK(pa1[6], pa1[7], 8);
        const float d0a = foldK(c01a, c23a, 16),      d0b = foldK(c01b, c23b, 16);
        const float d1a = foldK(c45a, c67a, 16),      d1b = foldK(c45b, c67b, 16);
        float e0 = foldK(d0a, d1a, 32);
        float e1 = foldK(d0b, d1b, 32);
        e0 += __shfl_xor(e0, 1, 64);  e1 += __shfl_xor(e1, 1, 64);
        e0 += __shfl_xor(e0, 2, 64);  e1 += __shfl_xor(e1, 2, 64);
        e0 += __shfl_xor(e0, 4, 64);  e1 += __shfl_xor(e1, 4, 64);

        int gm0, gm1;
        {
            const int a0 = (lane & 8) ? g0[1] : g0[0];
            const int a1 = (lane & 8) ? g0[3] : g0[2];
            const int a2 = (lane & 8) ? g0[5] : g0[4];
            const int a3 = (lane & 8) ? g0[7] : g0[6];
            const int b0 = (lane & 16) ? a1 : a0;
            const int b1 = (lane & 16) ? a3 : a2;
            gm0 = (lane & 32) ? b1 : b0;
            const int c0 = (lane & 8) ? g1[1] : g1[0];
            const int c1 = (lane & 8) ? g1[3] : g1[2];
            const int c2 = (lane & 8) ? g1[5] : g1[4];
            const int c3 = (lane & 8) ? g1[7] : g1[6];
            const int e0i = (lane & 16) ? c1 : c0;
            const int e1i = (lane & 16) ? c3 : c2;
            gm1 = (lane & 32) ? e1i : e0i;
        }
        float my0 = e0 + b_in[gm0];
        float my1 = e1 + b_in[gm1];

        // fp32 repair of near-zero logits, both rows (rare)
        if (d < DEPTH) {
            const unsigned long long bal0 = __ballot(fabsf(my0) < MARGIN);
            const unsigned long long bal1 = has1 ? __ballot(fabsf(my1) < MARGIN) : 0ULL;
            unsigned rm0 = 0, rm1 = 0;
            #pragma unroll
            for (int p = 0; p < PAR; ++p) {
                rm0 |= ((unsigned)((bal0 >> REPLANE(p)) & 1ULL)) << p;
                rm1 |= ((unsigned)((bal1 >> REPLANE(p)) & 1ULL)) << p;
            }
            if (rm0 | rm1) {
                #pragma unroll 1
                for (int r = 0; r < 2; ++r) {
                    unsigned rm = r ? rm1 : rm0;
                    if (!rm) continue;
                    const float* xrr = r ? xr1 : xr0;
                    const float4 fa = *(const float4*)(xrr + lane * 8 + 0);
                    const float4 fb = *(const float4*)(xrr + lane * 8 + 4);
                    const float4 fc = *(const float4*)(xrr + 512 + lane * 8 + 0);
                    const float4 fd = *(const float4*)(xrr + 512 + lane * 8 + 4);
                    while (rm) {
                        const int p = __builtin_ctz(rm); rm &= (rm - 1u);
                        const int gi = r ? g1[p] : g0[p];
                        const float* wr = W_in + (size_t)gi * DIM;
                        const float4 wa = *(const float4*)(wr + lane * 8 + 0);
                        const float4 wb = *(const float4*)(wr + lane * 8 + 4);
                        const float4 wc = *(const float4*)(wr + 512 + lane * 8 + 0);
                        const float4 wd = *(const float4*)(wr + 512 + lane * 8 + 4);
                        float s = 0.f;
                        s = fmaf(fa.x, wa.x, s); s = fmaf(fa.y, wa.y, s);
                        s = fmaf(fa.z, wa.z, s); s = fmaf(fa.w, wa.w, s);
                        s = fmaf(fb.x, wb.x, s); s = fmaf(fb.y, wb.y, s);
                        s = fmaf(fb.z, wb.z, s); s = fmaf(fb.w, wb.w, s);
                        s = fmaf(fc.x, wc.x, s); s = fmaf(fc.y, wc.y, s);
                        s = fmaf(fc.z, wc.z, s); s = fmaf(fc.w, wc.w, s);
                        s = fmaf(fd.x, wd.x, s); s = fmaf(fd.y, wd.y, s);
                        s = fmaf(fd.z, wd.z, s); s = fmaf(fd.w, wd.w, s);
                        #pragma unroll
                        for (int off = 32; off >= 1; off >>= 1)
                            s += __shfl_xor(s, off, 64);
                        const float lf = s + b_in[gi];
                        if (myp == p) { if (r) my1 = lf; else my0 = lf; }
                    }
                }
            }
        }

        // per-lane silu, ballot decisions (both rows)
        const float am0 = my0 / (1.0f + __expf(-my0));
        const float am1 = my1 / (1.0f + __expf(-my1));
        const unsigned long long pos0 = __ballot(my0 > 0.0f);
        const unsigned long long pos1 = __ballot(my1 > 0.0f);

        float act0[PAR], act1[PAR];
        #pragma unroll
        for (int p = 0; p < PAR; ++p) {
            act0[p] = __shfl(am0, REPLANE(p), 64);
            act1[p] = __shfl(am1, REPLANE(p), 64);
        }

        // Phase C: pk-fma axpy of bf16 WoT rows, both rows interleaved
        #pragma unroll
        for (int p = 0; p < PAR; ++p) {
            const unsigned short* wo0 = WoT + (size_t)g0[p] * DIM;
            const unsigned short* wo1 = WoT + (size_t)g1[p] * DIM;
            const uint4 u0 = *(const uint4*)(wo0 + lane * 8);
            const uint4 u1 = *(const uint4*)(wo0 + 512 + lane * 8);
            const uint4 v0 = *(const uint4*)(wo1 + lane * 8);
            const uint4 v1 = *(const uint4*)(wo1 + 512 + lane * 8);
            const float2v A0 = (float2v){act0[p], act0[p]};
            const float2v A1 = (float2v){act1[p], act1[p]};
            acc0[0] += A0 * (float2v){bf_lo(u0.x), bf_hi(u0.x)};
            acc0[1] += A0 * (float2v){bf_lo(u0.y), bf_hi(u0.y)};
            acc0[2] += A0 * (float2v){bf_lo(u0.z), bf_hi(u0.z)};
            acc0[3] += A0 * (float2v){bf_lo(u0.w), bf_hi(u0.w)};
            acc0[4] += A0 * (float2v){bf_lo(u1.x), bf_hi(u1.x)};
            acc0[5] += A0 * (float2v){bf_lo(u1.y), bf_hi(u1.y)};
            acc0[6] += A0 * (float2v){bf_lo(u1.z), bf_hi(u1.z)};
            acc0[7] += A0 * (float2v){bf_lo(u1.w), bf_hi(u1.w)};
            acc1[0] += A1 * (float2v){bf_lo(v0.x), bf_hi(v0.x)};
            acc1[1] += A1 * (float2v){bf_lo(v0.y), bf_hi(v0.y)};
            acc1[2] += A1 * (float2v){bf_lo(v0.z), bf_hi(v0.z)};
            acc1[3] += A1 * (float2v){bf_lo(v0.w), bf_hi(v0.w)};
            acc1[4] += A1 * (float2v){bf_lo(v1.x), bf_hi(v1.x)};
            acc1[5] += A1 * (float2v){bf_lo(v1.y), bf_hi(v1.y)};
            acc1[6] += A1 * (float2v){bf_lo(v1.z), bf_hi(v1.z)};
            acc1[7] += A1 * (float2v){bf_lo(v1.w), bf_hi(v1.w)};

            if (d < DEPTH) {
                const int np0 = (int)((nodes0 >> (8 * p)) & 0xffULL);
                const int np1 = (int)((nodes1 >> (8 * p)) & 0xffULL);
                const unsigned long long nn0 = (unsigned long long)
                    (2 * np0 + 1 + (int)((pos0 >> REPLANE(p)) & 1ULL));
                const unsigned long long nn1 = (unsigned long long)
                    (2 * np1 + 1 + (int)((pos1 >> REPLANE(p)) & 1ULL));
                nodes0 = (nodes0 & ~(0xffULL << (8 * p))) | (nn0 << (8 * p));
                nodes1 = (nodes1 & ~(0xffULL << (8 * p))) | (nn1 << (8 * p));
            }
        }
    }

    float* o0 = out + (size_t)r0 * DIM;
    *(float4*)(o0 + lane * 8 + 0)       = make_float4(acc0[0].x, acc0[0].y, acc0[1].x, acc0[1].y);
    *(float4*)(o0 + lane * 8 + 4)       = make_float4(acc0[2].x, acc0[2].y, acc0[3].x, acc0[3].y);
    *(float4*)(o0 + 512 + lane * 8 + 0) = make_float4(acc0[4].x, acc0[4].y, acc0[5].x, acc0[5].y);
    *(float4*)(o0 + 512 + lane * 8 + 4) = make_float4(acc0[6].x, acc0[6].y, acc0[7].x, acc0[7].y);
    if (has1) {
        float* o1 = out + (size_t)r1 * DIM;
        *(float4*)(o1 + lane * 8 + 0)       = make_float4(acc1[0].x, acc1[0].y, acc1[1].x, acc1[1].y);
        *(float4*)(o1 + lane * 8 + 4)       = make_float4(acc1[2].x, acc1[2].y, acc1[3].x, acc1[3].y);
        *(float4*)(o1 + 512 + lane * 8 + 0) = make_float4(acc1[4].x, acc1[4].y, acc1[5].x, acc1[5].y);
        *(float4*)(o1 + 512 + lane * 8 + 4) = make_float4(acc1[6].x, acc1[6].y, acc1[7].x, acc1[7].y);
    }
}

// ---------------------------------------------------------------------------
// Fallback (no workspace): fp32 gather both stages. Correct but slow.
// ---------------------------------------------------------------------------
__global__ __launch_bounds__(256) void fff_fallback_kernel(
    const float* __restrict__ x, const float* __restrict__ W_in,
    const float* __restrict__ b_in, const float* __restrict__ W_out,
    float* __restrict__ out, int B)
{
    const int wave = (int)((blockIdx.x * blockDim.x + threadIdx.x) >> 6);
    const int lane = (int)(threadIdx.x & 63);
    if (wave >= B) return;

    const float* xr = x + (size_t)wave * DIM;
    float4 x4[4];
    x4[0] = *(const float4*)(xr + lane * 8 + 0);
    x4[1] = *(const float4*)(xr + lane * 8 + 4);
    x4[2] = *(const float4*)(xr + 512 + lane * 8 + 0);
    x4[3] = *(const float4*)(xr + 512 + lane * 8 + 4);

    float acc[16];
    #pragma unroll
    for (int i = 0; i < 16; ++i) acc[i] = 0.f;
    int node[PAR];
    #pragma unroll
    for (int p = 0; p < PAR; ++p) node[p] = 0;

    for (int d = 0; d <= DEPTH; ++d) {
        #pragma unroll
        for (int p = 0; p < PAR; ++p) {
            const int gidx = p * N_NODES + node[p];
            const float* wr = W_in + (size_t)gidx * DIM;
            const float4 wa = *(const float4*)(wr + lane * 8 + 0);
            const float4 wb = *(const float4*)(wr + lane * 8 + 4);
            const float4 wc = *(const float4*)(wr + 512 + lane * 8 + 0);
            const float4 wd = *(const float4*)(wr + 512 + lane * 8 + 4);
            float s = 0.f;
            s = fmaf(x4[0].x, wa.x, s); s = fmaf(x4[0].y, wa.y, s);
            s = fmaf(x4[0].z, wa.z, s); s = fmaf(x4[0].w, wa.w, s);
            s = fmaf(x4[1].x, wb.x, s); s = fmaf(x4[1].y, wb.y, s);
            s = fmaf(x4[1].z, wb.z, s); s = fmaf(x4[1].w, wb.w, s);
            s = fmaf(x4[2].x, wc.x, s); s = fmaf(x4[2].y, wc.y, s);
            s = fmaf(x4[2].z, wc.z, s); s = fmaf(x4[2].w, wc.w, s);
            s = fmaf(x4[3].x, wd.x, s); s = fmaf(x4[3].y, wd.y, s);
            s = fmaf(x4[3].z, wd.z, s); s = fmaf(x4[3].w, wd.w, s);
            #pragma unroll
            for (int off = 32; off >= 1; off >>= 1)
                s += __shfl_xor(s, off, 64);
            const float logit = s + b_in[gidx];
            const float act = logit / (1.0f + __expf(-logit));
            #pragma unroll
            for (int k = 0; k < 2; ++k) {
                #pragma unroll
                for (int j = 0; j < 8; ++j) {
                    const int e = k * 512 + lane * 8 + j;
                    acc[k * 8 + j] = fmaf(act, W_out[(size_t)e * WIDTH + gidx], acc[k * 8 + j]);
                }
            }
            node[p] = 2 * node[p] + 1 + ((logit > 0.0f) ? 1 : 0);
        }
    }

    float* orow = out + (size_t)wave * DIM;
    *(float4*)(orow + lane * 8 + 0)       = make_float4(acc[0],  acc[1],  acc[2],  acc[3]);
    *(float4*)(orow + lane * 8 + 4)       = make_float4(acc[4],  acc[5],  acc[6],  acc[7]);
    *(float4*)(orow + 512 + lane * 8 + 0) = make_float4(acc[8],  acc[9],  acc[10], acc[11]);
    *(float4*)(orow + 512 + lane * 8 + 4) = make_float4(acc[12], acc[13], acc[14], acc[15]);
}

extern "C" void kernel_launch(void* const* d_in, const int* in_sizes, int n_in,
                              void* d_out, int out_size, void* d_ws, size_t ws_size,
                              hipStream_t stream) {
    const float* oldx  = (const float*)d_in[0];
    const float* W_in  = (const float*)d_in[1];
    const float* b_in  = (const float*)d_in[2];
    const float* W_out = (const float*)d_in[3];
    float* out = (float*)d_out;

    const int B = in_sizes[0] / DIM;   // 8192 rows

    const size_t half = (size_t)WIDTH * DIM * sizeof(unsigned short);  // 4.18 MB
    const bool use_lp = (ws_size >= 2 * half) && (d_ws != nullptr);

    if (use_lp) {
        unsigned short* WoT = (unsigned short*)d_ws;
        unsigned int*   Wh  = (unsigned int*)((char*)d_ws + half);
        dim3 tg((WIDTH + 63) / 64, DIM / 64);
        transpose_bf16_kernel<<<tg, 256, 0, stream>>>(W_out, WoT);
        const int n4 = WIDTH * DIM / 4;
        convert_f16_kernel<<<(n4 + 255) / 256, 256, 0, stream>>>(W_in, Wh, n4);
        const int npairs = (B + 1) / 2;                 // 4096 waves
        const int blocks = (npairs * 64 + 255) / 256;   // 1024 blocks
        fff_f16x2_kernel<<<blocks, 256, 0, stream>>>(oldx, W_in, b_in, Wh, WoT, out, B);
    } else {
        const int blocks = (B + 3) / 4;
        fff_fallback_kernel<<<blocks, 256, 0, stream>>>(oldx, W_in, b_in, W_out, out, B);
    }
}